// Round 6
// baseline (201.823 us; speedup 1.0000x reference)
//
#include <hip/hip_runtime.h>

#define B_SZ   128
#define T_SEQ  256
#define C_DIM  384
#define HEADS  6
#define HD     64
#define WIN    64

typedef __bf16 bf16x8 __attribute__((ext_vector_type(8)));
typedef float  f32x4  __attribute__((ext_vector_type(4)));

typedef __attribute__((address_space(3))) void lds_void;
typedef __attribute__((address_space(1))) void gbl_void;

__device__ __forceinline__ unsigned short f2bf(float f) {
  unsigned u = __float_as_uint(f);
  u += 0x7FFFu + ((u >> 16) & 1u);   // RNE
  return (unsigned short)(u >> 16);
}

// ===========================================================================
// PACKED OPERAND LAYOUT for GEMM staging (unchanged from r4):
//   [tile128][kchunk(=K/32)][row128][32] bf16, LDS XOR swizzle pre-applied:
//   16-B unit u of row r stored at p = u ^ ((r&7)>>1). global_load_lds reads
//   1 KB fully contiguous; LDS image identical to scatter-staged version.
//
// qkv written by GEMM1 in ATTN-NATIVE PANES qkv2[B][3][H][T_SEQ][64] bf16;
// Q/K panes carry the attn LDS swizzle pre-baked (granule u of row tpos at
// position u ^ (tpos&7)); V panes linear.
//
// r6 FIX: GEMM1 pane stores are now MONOTONIC per lane (linear pane
// address); the XOR permutation is applied to the ep LDS READ index instead.
// r5's permuted stores broke lane-adjacency (8x16-B runs per 128-B row) ->
// TA coalescer serialization + write-allocate FETCH inflation (15.8->20 MB),
// costing GEMM1 ~13 us. Permuting the LDS read is free (same address set
// per 16-lane group -> same bank profile).
// ===========================================================================

// ---------------------------------------------------------------------------
// fp32 [M,384] -> packed pre-swizzled bf16. One 8-elem unit per thread.
// grid*256 == M*48 exactly.
// ---------------------------------------------------------------------------
__global__ __launch_bounds__(256) void convert_pack_f32_bf16(
    const float* __restrict__ in, unsigned short* __restrict__ out) {
  const int tid = blockIdx.x * 256 + threadIdx.x;
  const int m   = tid / 48;        // global row
  const int rem = tid % 48;
  const int kc  = rem >> 2;        // k-chunk 0..11
  const int u   = rem & 3;         // 16-B unit within chunk
  const float4 a = *(const float4*)(in + (size_t)m * 384 + kc * 32 + u * 8);
  const float4 b = *(const float4*)(in + (size_t)m * 384 + kc * 32 + u * 8 + 4);
  const int p = u ^ ((m & 7) >> 1);
  unsigned short* dst =
      out + ((size_t)(m >> 7) * 12 + kc) * 4096 + (m & 127) * 32 + p * 8;
  ushort4 o1, o2;
  o1.x = f2bf(a.x); o1.y = f2bf(a.y); o1.z = f2bf(a.z); o1.w = f2bf(a.w);
  o2.x = f2bf(b.x); o2.y = f2bf(b.y); o2.z = f2bf(b.z); o2.w = f2bf(b.w);
  *(ushort4*)dst = o1;
  *(ushort4*)(dst + 4) = o2;
}

// ---------------------------------------------------------------------------
// W[K,N] fp32 -> packed pre-swizzled bf16 Wt (N-major tiles), via 32x32 LDS
// tile transpose. Scalar packed stores (weights are small).
// ---------------------------------------------------------------------------
__global__ __launch_bounds__(256) void transpose_convert_pack(
    const float* __restrict__ in, unsigned short* __restrict__ out,
    int K, int N) {
  __shared__ float tile[32][33];
  const int gx = blockIdx.x * 32;  // n
  const int gy = blockIdx.y * 32;  // k
  const int tx = threadIdx.x;      // 0..31
  const int ty = threadIdx.y;      // 0..7
#pragma unroll
  for (int r = ty; r < 32; r += 8)
    tile[r][tx] = in[(size_t)(gy + r) * N + gx + tx];
  __syncthreads();
  const int nkc = K >> 5;
#pragma unroll
  for (int r = ty; r < 32; r += 8) {
    const int n = gx + r;
    const int k = gy + tx;
    const int p = (((k >> 3) & 3) ^ ((n & 7) >> 1));
    out[((size_t)(n >> 7) * nkc + (k >> 5)) * 4096 + (n & 127) * 32 + p * 8 +
        (k & 7)] = f2bf(tile[tx][r]);
  }
}

// ---------------------------------------------------------------------------
// bf16 MFMA GEMM: C[M,N] = A[M,K] @ Bt[N,K]^T + bias[N]; A,Bt PACKED layout.
// 128x128 tile, BK=32, triple-buffered 2-deep pipeline, counted vmcnt(4) +
// lgkmcnt(0) before raw s_barrier (race fix r4). 4 waves, 64x64 quadrants.
// OUT_BF16=true (GEMM1): C written into qkv2 attn panes, monotonic stores,
// swizzle applied on the ep LDS read (r6 fix). OUT_BF16=false: fp32 rowmajor.
// ---------------------------------------------------------------------------
template <bool OUT_BF16, int KK>
__global__ __launch_bounds__(256, 3) void gemm_mfma_bf16(
    const unsigned short* __restrict__ A,   // packed [M/128][KK/32][128][32]
    const unsigned short* __restrict__ Bt,  // packed [N/128][KK/32][128][32]
    const float* __restrict__ bias,
    void* __restrict__ Cv, int M, int N, int tiles_n) {
  __shared__ __attribute__((aligned(16))) char smem_raw[49152];  // 3x16 KB
  float* ep = (float*)smem_raw;                      // 64 x 132 fp32 epilogue

  constexpr int NK = KK / 32;

  const int t    = threadIdx.x;
  const int lane = t & 63;
  const int w    = t >> 6;
  const int wr   = w >> 1;   // wave row (0..1): 64 M-rows
  const int wc   = w & 1;    // wave col (0..1): 64 N-cols

  // XCD-grouped remap: consecutive slabs per XCD; bx fastest -> same A panel.
  const unsigned id    = blockIdx.x;
  const unsigned remap = (id & 7u) * (gridDim.x >> 3) + (id >> 3);
  const int by = remap / (unsigned)tiles_n;
  const int bx = remap % (unsigned)tiles_n;
  const int m0 = by * 128;
  const int n0 = bx * 128;

  const unsigned short* Atile = A  + (size_t)by * NK * 4096;
  const unsigned short* Btile = Bt + (size_t)bx * NK * 4096;

  const int m16  = lane & 15;
  const int quad = lane >> 4;
  const int cp   = (quad ^ ((m16 >> 1) & 3)) << 3;  // frag chunk (shorts)

  f32x4 acc[4][4];
#pragma unroll
  for (int i = 0; i < 4; ++i)
#pragma unroll
    for (int j = 0; j < 4; ++j) acc[i][j] = (f32x4){0.f, 0.f, 0.f, 0.f};

  // each wave issues exactly 4 contiguous 1-KB global_load_lds per stage
  auto stage = [&](int slot, int kc) {
    unsigned short* Ad = (unsigned short*)(smem_raw + slot * 16384);
    unsigned short* Bd = Ad + 128 * 32;
    const unsigned short* ta = Atile + (size_t)kc * 4096;
    const unsigned short* tb = Btile + (size_t)kc * 4096;
#pragma unroll
    for (int i = 0; i < 2; ++i) {
      const int inst = w * 2 + i;           // 0..7, 16 rows each
      __builtin_amdgcn_global_load_lds(
          (const gbl_void*)(ta + inst * 512 + lane * 8),
          (lds_void*)(Ad + inst * 512), 16, 0, 0);
      __builtin_amdgcn_global_load_lds(
          (const gbl_void*)(tb + inst * 512 + lane * 8),
          (lds_void*)(Bd + inst * 512), 16, 0, 0);
    }
  };

  stage(0, 0);
  stage(1, 1);

#pragma unroll
  for (int kt = 0; kt < NK; ++kt) {
    // vmcnt(4): tile kt landed (kt+1 stays in flight).
    // lgkmcnt(0): THIS wave's ds_reads of slot (kt-1)%3 have COMPLETED, so
    // the post-barrier stage(kt+2) overwrite of that slot cannot race them.
    if (kt + 1 < NK)
      asm volatile("s_waitcnt vmcnt(4) lgkmcnt(0)" ::: "memory");
    else
      asm volatile("s_waitcnt vmcnt(0) lgkmcnt(0)" ::: "memory");
    __builtin_amdgcn_s_barrier();
    __builtin_amdgcn_sched_barrier(0);

    if (kt + 2 < NK) stage((kt + 2) % 3, kt + 2);

    const unsigned short* Ac =
        (const unsigned short*)(smem_raw + (kt % 3) * 16384);
    const unsigned short* Bc = Ac + 128 * 32;

    bf16x8 af[4];
#pragma unroll
    for (int mt = 0; mt < 4; ++mt)
      af[mt] = *(const bf16x8*)(Ac + (size_t)(wr * 64 + mt * 16 + m16) * 32 + cp);
#pragma unroll
    for (int nt = 0; nt < 4; ++nt) {
      bf16x8 bfr = *(const bf16x8*)(Bc + (size_t)(wc * 64 + nt * 16 + m16) * 32 + cp);
#pragma unroll
      for (int mt = 0; mt < 4; ++mt)
        acc[mt][nt] = __builtin_amdgcn_mfma_f32_16x16x32_bf16(
            af[mt], bfr, acc[mt][nt], 0, 0, 0);
    }
  }
  __syncthreads();  // all tile reads done; LDS free for epilogue reuse.

  float bv[4];
#pragma unroll
  for (int nt = 0; nt < 4; ++nt) bv[nt] = bias[n0 + wc * 64 + nt * 16 + m16];

  // qkv-pane decomposition of this block's 128 N-cols (OUT_BF16 path):
  // cols n0..n0+127 = which = bx/3 (never crosses), heads hbase, hbase+1.
  const int which = bx / 3;
  const int hbase = (bx % 3) * 2;

  // ---- epilogue: 2 passes; wave-row p dumps its 64 rows, all store ----
#pragma unroll
  for (int p = 0; p < 2; ++p) {
    if (p) __syncthreads();  // prior pass reads done before overwrite
    if (wr == p) {
#pragma unroll
      for (int mt = 0; mt < 4; ++mt)
#pragma unroll
        for (int nt = 0; nt < 4; ++nt)
#pragma unroll
          for (int r = 0; r < 4; ++r)
            ep[(mt * 16 + quad * 4 + r) * 132 + wc * 64 + nt * 16 + m16] =
                acc[mt][nt][r] + bv[nt];
    }
    __syncthreads();
    // 64 rows x 32 float4-chunks = 2048 chunks, 8 per thread, coalesced
#pragma unroll
    for (int cc = 0; cc < 8; ++cc) {
      const int chunk = cc * 256 + t;
      const int row = chunk >> 5;
      const int c4  = chunk & 31;
      const int grow = m0 + p * 64 + row;
      if (OUT_BF16) {
        // qkv2 pane store, MONOTONIC: lane -> linear pane address; the attn
        // swizzle is applied to the ep READ column instead (r6 fix).
        const int hh  = c4 >> 4;        // head within block's pair
        const int g16 = c4 & 15;        // ushort4 slot within 64-short row
        const int s   = (which == 2) ? 0 : (row & 7);  // tp&7 == row&7
        const int col = hh * 64 + ((((g16 >> 1) ^ s) << 3) | ((g16 & 1) << 2));
        f32x4 v = *(const f32x4*)(ep + row * 132 + col);
        ushort4 o;
        o.x = f2bf(v[0]); o.y = f2bf(v[1]); o.z = f2bf(v[2]); o.w = f2bf(v[3]);
        const int b_ = grow >> 8;
        const int tp = grow & 255;
        *(ushort4*)((unsigned short*)Cv +
                    ((size_t)((b_ * 3 + which) * HEADS + hbase + hh) * T_SEQ +
                     tp) * HD + g16 * 4) = o;
      } else {
        f32x4 v = *(const f32x4*)(ep + row * 132 + c4 * 4);
        const int gcol = n0 + c4 * 4;
        *(f32x4*)((float*)Cv + (size_t)grow * N + gcol) = v;
      }
    }
  }
}

// ---------------------------------------------------------------------------
// Banded causal attention via bf16 MFMA, fp32 softmax. qkv comes in
// attn-native panes [B][3][H][256][64] with Q/K pre-swizzled: staging is
// fully-linear 1-KB global_load_lds; V reads stay inside one contiguous
// L1-resident 8-KB pane window. Output y packed for GEMM2.
// ---------------------------------------------------------------------------
#define PSTR 68
__global__ __launch_bounds__(256) void attn_mfma(
    const unsigned short* __restrict__ qkv, unsigned short* __restrict__ y) {
  __shared__ unsigned short Qs[64 * 64];   // [qrow][d]  bf16, swizzled
  __shared__ unsigned short Ks[64 * 64];   // [key][d]   bf16, swizzled
  __shared__ unsigned short Vt[64 * 64];   // [d][key]   bf16, swizzled
  __shared__ float Pw[4][16 * PSTR];       // per-wave P; reused as y-stage

  const unsigned id  = blockIdx.x;
  const unsigned bid = (id & 7u) * (gridDim.x >> 3) + (id >> 3);
  const int qt  = bid & 3;
  const int h   = (bid >> 2) % HEADS;
  const int b   = bid / (4 * HEADS);
  const int t   = threadIdx.x;
  const int lane = t & 63;
  const int w    = t >> 6;
  const int quad = lane >> 4;
  const int m16  = lane & 15;
  const int sw   = m16 & 7;

  const unsigned short* Qpane =
      qkv + ((size_t)((b * 3 + 0) * HEADS + h) * T_SEQ) * HD;
  const unsigned short* Kpane =
      qkv + ((size_t)((b * 3 + 1) * HEADS + h) * T_SEQ) * HD;
  const unsigned short* Vpane =
      qkv + ((size_t)((b * 3 + 2) * HEADS + h) * T_SEQ) * HD;
  const int qg0 = qt * 64;

  // ---- stage Q (64x64 bf16): linear 1-KB DMA, swizzle pre-baked ----
#pragma unroll
  for (int i = 0; i < 2; ++i) {
    const int inst = w * 2 + i;
    __builtin_amdgcn_global_load_lds(
        (const gbl_void*)(Qpane + (size_t)qg0 * HD + inst * 512 + lane * 8),
        (lds_void*)(Qs + inst * 512), 16, 0, 0);
  }

  float m_r[4], l_r[4];
  f32x4 yacc[4];
#pragma unroll
  for (int r = 0; r < 4; ++r) { m_r[r] = -1e30f; l_r[r] = 0.f; }
#pragma unroll
  for (int dt = 0; dt < 4; ++dt) yacc[dt] = (f32x4){0.f, 0.f, 0.f, 0.f};

  const int nchunks  = (qt == 0) ? 1 : 2;
  const int kb_first = (qt == 0) ? 0 : (qg0 - 64);
  const int qrow_base = qg0 + w * 16 + quad * 4;

  for (int ch = 0; ch < nchunks; ++ch) {
    const int kb = kb_first + ch * 64;

    __syncthreads();  // drain staging; protect Ks/Vt from prior cross-wave reads

    // ---- stage K: linear 1-KB DMA, swizzle pre-baked ----
#pragma unroll
    for (int i = 0; i < 2; ++i) {
      const int inst = w * 2 + i;
      __builtin_amdgcn_global_load_lds(
          (const gbl_void*)(Kpane + (size_t)kb * HD + inst * 512 + lane * 8),
          (lds_void*)(Ks + inst * 512), 16, 0, 0);
    }
    // ---- stage V transposed, swizzled: Vt[d][pos] = keychunk pos^(d&7) ----
    // reads land inside one contiguous 8-KB pane window (L1-resident)
    {
      const int vkey = t & 63;
      const int kc = vkey >> 3, ke = vkey & 7;
      const int vd0  = (t >> 6) * 16;
      const unsigned short* gv = Vpane + (size_t)(kb + vkey) * HD + vd0;
#pragma unroll
      for (int u = 0; u < 4; ++u) {
        ushort4 vv = *(const ushort4*)(gv + u * 4);
#pragma unroll
        for (int jj = 0; jj < 4; ++jj) {
          const int d = vd0 + u * 4 + jj;
          const unsigned short val =
              (jj == 0) ? vv.x : (jj == 1) ? vv.y : (jj == 2) ? vv.z : vv.w;
          Vt[d * 64 + ((kc ^ (d & 7)) << 3) + ke] = val;
        }
      }
    }
    __syncthreads();

    // ---- QK^T: S[16q x 64key] ----
    f32x4 sacc[4];
#pragma unroll
    for (int nt = 0; nt < 4; ++nt) sacc[nt] = (f32x4){0.f, 0.f, 0.f, 0.f};
#pragma unroll
    for (int ks = 0; ks < 64; ks += 32) {
      const int cp = (((ks >> 3) + quad) ^ sw) << 3;
      bf16x8 aq = *(const bf16x8*)(Qs + (size_t)(w * 16 + m16) * 64 + cp);
#pragma unroll
      for (int nt = 0; nt < 4; ++nt) {
        bf16x8 kf = *(const bf16x8*)(Ks + (size_t)(nt * 16 + m16) * 64 + cp);
        sacc[nt] = __builtin_amdgcn_mfma_f32_16x16x32_bf16(aq, kf, sacc[nt], 0, 0, 0);
      }
    }

    // ---- scale + band mask (C-layout: row=quad*4+r, col=m16) ----
    float mc[4] = {-1e30f, -1e30f, -1e30f, -1e30f};
#pragma unroll
    for (int nt = 0; nt < 4; ++nt) {
      const int kg = kb + nt * 16 + m16;
#pragma unroll
      for (int r = 0; r < 4; ++r) {
        const int qg = qrow_base + r;
        const bool valid = (kg <= qg) && (qg - kg <= WIN);
        const float sv = valid ? (sacc[nt][r] * 0.125f) : -1e30f;
        sacc[nt][r] = sv;
        mc[r] = fmaxf(mc[r], sv);
      }
    }
#pragma unroll
    for (int r = 0; r < 4; ++r) {
#pragma unroll
      for (int x = 1; x <= 8; x <<= 1) mc[r] = fmaxf(mc[r], __shfl_xor(mc[r], x));
    }

    // ---- online softmax update ----
#pragma unroll
    for (int r = 0; r < 4; ++r) {
      const float mn    = fmaxf(m_r[r], mc[r]);
      const float alpha = __expf(m_r[r] - mn);
      m_r[r] = mn;
      l_r[r] *= alpha;
#pragma unroll
      for (int dt = 0; dt < 4; ++dt) yacc[dt][r] *= alpha;
      float ls = 0.f;
#pragma unroll
      for (int nt = 0; nt < 4; ++nt) {
        const float p = __expf(sacc[nt][r] - mn);
        sacc[nt][r] = p;
        ls += p;
      }
#pragma unroll
      for (int x = 1; x <= 8; x <<= 1) ls += __shfl_xor(ls, x);
      l_r[r] += ls;
    }

    // ---- write P (fp32) to per-wave LDS (wave-private: no barrier needed;
    //      in-wave DS ordering + compiler lgkmcnt guard the RAW) ----
#pragma unroll
    for (int nt = 0; nt < 4; ++nt)
#pragma unroll
      for (int r = 0; r < 4; ++r)
        Pw[w][(quad * 4 + r) * PSTR + nt * 16 + m16] = sacc[nt][r];

    // ---- PV: A = P-frag (fp32->bf16), B = Vt-frag ----
#pragma unroll
    for (int ks = 0; ks < 64; ks += 32) {
      f32x4 pa = *(const f32x4*)(&Pw[w][m16 * PSTR + ks + quad * 8]);
      f32x4 pb = *(const f32x4*)(&Pw[w][m16 * PSTR + ks + quad * 8 + 4]);
      bf16x8 ap;
#pragma unroll
      for (int j = 0; j < 4; ++j) {
        ap[j]     = (__bf16)pa[j];
        ap[4 + j] = (__bf16)pb[j];
      }
      const int cp = (((ks >> 3) + quad) ^ sw) << 3;
#pragma unroll
      for (int dt = 0; dt < 4; ++dt) {
        bf16x8 vf = *(const bf16x8*)(Vt + (size_t)(dt * 16 + m16) * 64 + cp);
        yacc[dt] = __builtin_amdgcn_mfma_f32_16x16x32_bf16(ap, vf, yacc[dt], 0, 0, 0);
      }
    }
  }

  // ---- epilogue: stage y/l into Pw (wave-local region), packed stores ----
  float* epy = &Pw[0][0];  // viewed as [64 rows][68]; rows w*16.. are Pw[w]
  float inv[4];
#pragma unroll
  for (int r = 0; r < 4; ++r) inv[r] = 1.f / l_r[r];
#pragma unroll
  for (int dt = 0; dt < 4; ++dt)
#pragma unroll
    for (int r = 0; r < 4; ++r)
      epy[(w * 16 + quad * 4 + r) * PSTR + dt * 16 + m16] = yacc[dt][r] * inv[r];
  __syncthreads();
  // 64 rows x 16 ushort4-chunks = 1024 chunks, 4 per thread.
  // Store into PACKED pre-swizzled y layout [M/128][12][128][32].
#pragma unroll
  for (int cc = 0; cc < 4; ++cc) {
    const int chunk = cc * 256 + t;
    const int row = chunk >> 4;
    const int c4  = chunk & 15;
    f32x4 v = *(const f32x4*)(epy + row * PSTR + c4 * 4);
    ushort4 o;
    o.x = f2bf(v[0]); o.y = f2bf(v[1]); o.z = f2bf(v[2]); o.w = f2bf(v[3]);
    const int m = b * T_SEQ + qg0 + row;   // global row
    const int c = h * HD + c4 * 4;         // global col
    const int kc = c >> 5;
    const int u  = (c >> 3) & 3;
    const int p  = u ^ ((m & 7) >> 1);
    *(ushort4*)(y + ((size_t)(m >> 7) * 12 + kc) * 4096 + (m & 127) * 32 +
                p * 8 + (c & 7)) = o;
  }
}

// ---------------------------------------------------------------------------
extern "C" void kernel_launch(void* const* d_in, const int* in_sizes, int n_in,
                              void* d_out, int out_size, void* d_ws, size_t ws_size,
                              hipStream_t stream) {
  const float* x      = (const float*)d_in[0];
  const float* W_attn = (const float*)d_in[1];
  const float* b_attn = (const float*)d_in[2];
  const float* W_proj = (const float*)d_in[3];
  const float* b_proj = (const float*)d_in[4];
  float* out = (float*)d_out;

  const int M = B_SZ * T_SEQ;  // 32768

  unsigned short* qkv_b = (unsigned short*)d_ws;            // M*1152 bf16 (attn panes)
  unsigned short* y_b   = qkv_b + (size_t)M * (3 * C_DIM);  // M*384 (packed)
  unsigned short* x_b   = y_b   + (size_t)M * C_DIM;        // M*384 (packed)
  unsigned short* Wa_t  = x_b   + (size_t)M * C_DIM;        // 1152*384 (packed)
  unsigned short* Wp_t  = Wa_t  + (size_t)(3 * C_DIM) * C_DIM;  // 384*384 (packed)

  // 0) converts + packing
  {
    convert_pack_f32_bf16<<<dim3(M * 48 / 256), 256, 0, stream>>>(x, x_b);
    transpose_convert_pack<<<dim3((3 * C_DIM) / 32, C_DIM / 32), dim3(32, 8), 0,
                             stream>>>(W_attn, Wa_t, C_DIM, 3 * C_DIM);
    transpose_convert_pack<<<dim3(C_DIM / 32, C_DIM / 32), dim3(32, 8), 0,
                             stream>>>(W_proj, Wp_t, C_DIM, C_DIM);
  }

  // 1) qkv(bf16, attn panes) = x @ W_attn + b_attn   [32768 x 1152]
  gemm_mfma_bf16<true, C_DIM><<<dim3(9 * (M / 128)), 256, 0, stream>>>(
      x_b, Wa_t, b_attn, qkv_b, M, 3 * C_DIM, 9);

  // 2) banded causal attention -> y(bf16, packed) [32768 x 384]
  attn_mfma<<<dim3(B_SZ * HEADS * (T_SEQ / 64)), 256, 0, stream>>>(qkv_b, y_b);

  // 3) out(fp32) = y @ W_proj + b_proj   [32768 x 384], 256x3 tiles of 128x128
  gemm_mfma_bf16<false, C_DIM><<<dim3(3 * (M / 128)), 256, 0, stream>>>(
      y_b, Wp_t, b_proj, out, M, C_DIM, 3);
}

// Round 7
// 189.297 us; speedup vs baseline: 1.0662x; 1.0662x over previous
//
#include <hip/hip_runtime.h>

#define B_SZ   128
#define T_SEQ  256
#define C_DIM  384
#define HEADS  6
#define HD     64
#define WIN    64

typedef __bf16 bf16x8 __attribute__((ext_vector_type(8)));
typedef float  f32x4  __attribute__((ext_vector_type(4)));

typedef __attribute__((address_space(3))) void lds_void;
typedef __attribute__((address_space(1))) void gbl_void;

__device__ __forceinline__ unsigned short f2bf(float f) {
  unsigned u = __float_as_uint(f);
  u += 0x7FFFu + ((u >> 16) & 1u);   // RNE
  return (unsigned short)(u >> 16);
}

// ===========================================================================
// PACKED OPERAND LAYOUT (unchanged): [panel128][kchunk][row128][32] bf16,
// swizzle p = u ^ ((row&7)>>1) pre-applied. qkv in attn panes
// [B][3][H][256][64], Q/K panes attn-swizzled (granule u ^ (tpos&7)).
//
// r7: GEMM geometry 128x128/4-wave -> 256x128/8-wave (512 thr).
//   - occupancy: LDS 3x24 KB = 72 KB -> 2 blocks/CU = 16 waves/CU
//     (4 waves/SIMD, 2x round-6's 2.1) -- targets the 26% occupancy +
//     latency-bound signature (MfmaUtil 23 / VALU 22 / HBM 24, none bound).
//   - staged traffic -27% (B-tile reused over 256 A-rows).
//   - per-wave step work unchanged: 3 staging loads, 8 ds_read, 16 MFMA.
//   - same triple-buffer 2-deep pipeline, counted vmcnt(3) + lgkmcnt(0)
//     before s_barrier (r4 race discipline).
// ===========================================================================

// ---------------------------------------------------------------------------
// fp32 [M,384] -> packed pre-swizzled bf16. One 8-elem unit per thread.
// ---------------------------------------------------------------------------
__global__ __launch_bounds__(256) void convert_pack_f32_bf16(
    const float* __restrict__ in, unsigned short* __restrict__ out) {
  const int tid = blockIdx.x * 256 + threadIdx.x;
  const int m   = tid / 48;        // global row
  const int rem = tid % 48;
  const int kc  = rem >> 2;        // k-chunk 0..11
  const int u   = rem & 3;         // 16-B unit within chunk
  const float4 a = *(const float4*)(in + (size_t)m * 384 + kc * 32 + u * 8);
  const float4 b = *(const float4*)(in + (size_t)m * 384 + kc * 32 + u * 8 + 4);
  const int p = u ^ ((m & 7) >> 1);
  unsigned short* dst =
      out + ((size_t)(m >> 7) * 12 + kc) * 4096 + (m & 127) * 32 + p * 8;
  ushort4 o1, o2;
  o1.x = f2bf(a.x); o1.y = f2bf(a.y); o1.z = f2bf(a.z); o1.w = f2bf(a.w);
  o2.x = f2bf(b.x); o2.y = f2bf(b.y); o2.z = f2bf(b.z); o2.w = f2bf(b.w);
  *(ushort4*)dst = o1;
  *(ushort4*)(dst + 4) = o2;
}

// ---------------------------------------------------------------------------
// W[K,N] fp32 -> packed pre-swizzled bf16 Wt (N-major tiles).
// ---------------------------------------------------------------------------
__global__ __launch_bounds__(256) void transpose_convert_pack(
    const float* __restrict__ in, unsigned short* __restrict__ out,
    int K, int N) {
  __shared__ float tile[32][33];
  const int gx = blockIdx.x * 32;  // n
  const int gy = blockIdx.y * 32;  // k
  const int tx = threadIdx.x;      // 0..31
  const int ty = threadIdx.y;      // 0..7
#pragma unroll
  for (int r = ty; r < 32; r += 8)
    tile[r][tx] = in[(size_t)(gy + r) * N + gx + tx];
  __syncthreads();
  const int nkc = K >> 5;
#pragma unroll
  for (int r = ty; r < 32; r += 8) {
    const int n = gx + r;
    const int k = gy + tx;
    const int p = (((k >> 3) & 3) ^ ((n & 7) >> 1));
    out[((size_t)(n >> 7) * nkc + (k >> 5)) * 4096 + (n & 127) * 32 + p * 8 +
        (k & 7)] = f2bf(tile[tx][r]);
  }
}

// ---------------------------------------------------------------------------
// bf16 MFMA GEMM: C[M,N] = A[M,K] @ Bt[N,K]^T + bias[N]; packed operands.
// 256x128 tile, BK=32, 512 threads / 8 waves, wave = 64x64 quadrant
// (wr=w>>1 in 0..3, wc=w&1). Triple-buffered 24-KB slots, counted vmcnt(3).
// ---------------------------------------------------------------------------
template <bool OUT_BF16, int KK>
__global__ __launch_bounds__(512, 4) void gemm_mfma_bf16(
    const unsigned short* __restrict__ A,   // packed [M/128][KK/32][128][32]
    const unsigned short* __restrict__ Bt,  // packed [N/128][KK/32][128][32]
    const float* __restrict__ bias,
    void* __restrict__ Cv, int M, int N, int tiles_n) {
  __shared__ __attribute__((aligned(16))) char smem_raw[73728];  // 3x24 KB
  float* ep = (float*)smem_raw;                      // 64 x 132 fp32 epilogue

  constexpr int NK = KK / 32;

  const int t    = threadIdx.x;
  const int lane = t & 63;
  const int w    = t >> 6;   // 0..7
  const int wr   = w >> 1;   // wave row band (0..3): 64 M-rows each
  const int wc   = w & 1;    // wave col band (0..1): 64 N-cols each

  const unsigned id    = blockIdx.x;
  const unsigned remap = (id & 7u) * (gridDim.x >> 3) + (id >> 3);
  const int by = remap / (unsigned)tiles_n;
  const int bx = remap % (unsigned)tiles_n;
  const int m0 = by * 256;
  const int n0 = bx * 128;

  // A spans two consecutive 128-row panels; B one panel.
  const unsigned short* Ap0 = A  + (size_t)(by * 2)     * NK * 4096;
  const unsigned short* Ap1 = A  + (size_t)(by * 2 + 1) * NK * 4096;
  const unsigned short* Btile = Bt + (size_t)bx * NK * 4096;

  const int m16  = lane & 15;
  const int quad = lane >> 4;
  const int cp   = (quad ^ ((m16 >> 1) & 3)) << 3;  // frag chunk (shorts)

  f32x4 acc[4][4];
#pragma unroll
  for (int i = 0; i < 4; ++i)
#pragma unroll
    for (int j = 0; j < 4; ++j) acc[i][j] = (f32x4){0.f, 0.f, 0.f, 0.f};

  // 24 1-KB staging instrs/step: ids 0..15 = A (panel id>>3, sub id&7),
  // ids 16..23 = B. Wave w issues ids w*3..w*3+2 -> exactly 3 per stage.
  auto stage = [&](int slot, int kc) {
    unsigned short* As = (unsigned short*)(smem_raw + slot * 24576);
    unsigned short* Bs = As + 256 * 32;   // +16 KB
#pragma unroll
    for (int i = 0; i < 3; ++i) {
      const int idx = w * 3 + i;
      if (idx < 16) {
        const unsigned short* src =
            ((idx >> 3) ? Ap1 : Ap0) + (size_t)kc * 4096 + (idx & 7) * 512 +
            lane * 8;
        __builtin_amdgcn_global_load_lds((const gbl_void*)src,
                                         (lds_void*)(As + idx * 512), 16, 0, 0);
      } else {
        const int sub = idx - 16;
        const unsigned short* src =
            Btile + (size_t)kc * 4096 + sub * 512 + lane * 8;
        __builtin_amdgcn_global_load_lds((const gbl_void*)src,
                                         (lds_void*)(Bs + sub * 512), 16, 0, 0);
      }
    }
  };

  stage(0, 0);
  stage(1, 1);

#pragma unroll
  for (int kt = 0; kt < NK; ++kt) {
    // vmcnt(3): this wave's 3 loads of tile kt landed (kt+1 in flight).
    // lgkmcnt(0): this wave's ds_reads of slot (kt-1)%3 completed, so the
    // post-barrier stage(kt+2) overwrite of that slot cannot race them.
    if (kt + 1 < NK)
      asm volatile("s_waitcnt vmcnt(3) lgkmcnt(0)" ::: "memory");
    else
      asm volatile("s_waitcnt vmcnt(0) lgkmcnt(0)" ::: "memory");
    __builtin_amdgcn_s_barrier();
    __builtin_amdgcn_sched_barrier(0);

    if (kt + 2 < NK) stage((kt + 2) % 3, kt + 2);

    const unsigned short* As =
        (const unsigned short*)(smem_raw + (kt % 3) * 24576);
    const unsigned short* Bs = As + 256 * 32;

    bf16x8 af[4];
#pragma unroll
    for (int mt = 0; mt < 4; ++mt)
      af[mt] = *(const bf16x8*)(As + (size_t)(wr * 64 + mt * 16 + m16) * 32 + cp);
#pragma unroll
    for (int nt = 0; nt < 4; ++nt) {
      bf16x8 bfr = *(const bf16x8*)(Bs + (size_t)(wc * 64 + nt * 16 + m16) * 32 + cp);
#pragma unroll
      for (int mt = 0; mt < 4; ++mt)
        acc[mt][nt] = __builtin_amdgcn_mfma_f32_16x16x32_bf16(
            af[mt], bfr, acc[mt][nt], 0, 0, 0);
    }
  }
  __syncthreads();  // all tile reads done; LDS free for epilogue reuse.

  float bv[4];
#pragma unroll
  for (int nt = 0; nt < 4; ++nt) bv[nt] = bias[n0 + wc * 64 + nt * 16 + m16];

  // qkv-pane decomposition (OUT_BF16): which = bx/3, heads hbase, hbase+1.
  const int which = bx / 3;
  const int hbase = (bx % 3) * 2;

  // ---- epilogue: 4 passes; wave-row band p dumps its 64 rows ----
#pragma unroll
  for (int p = 0; p < 4; ++p) {
    if (p) __syncthreads();  // prior pass reads done before overwrite
    if (wr == p) {
#pragma unroll
      for (int mt = 0; mt < 4; ++mt)
#pragma unroll
        for (int nt = 0; nt < 4; ++nt)
#pragma unroll
          for (int r = 0; r < 4; ++r)
            ep[(mt * 16 + quad * 4 + r) * 132 + wc * 64 + nt * 16 + m16] =
                acc[mt][nt][r] + bv[nt];
    }
    __syncthreads();
    // 64 rows x 32 float4-chunks = 2048 chunks, 4 per thread, coalesced
#pragma unroll
    for (int cc = 0; cc < 4; ++cc) {
      const int chunk = cc * 512 + t;
      const int row = chunk >> 5;
      const int c4  = chunk & 31;
      const int grow = m0 + p * 64 + row;
      if (OUT_BF16) {
        // qkv2 pane store, monotonic; attn swizzle applied on ep READ col.
        const int hh  = c4 >> 4;
        const int g16 = c4 & 15;
        const int s   = (which == 2) ? 0 : (row & 7);  // tp&7 == row&7
        const int col = hh * 64 + ((((g16 >> 1) ^ s) << 3) | ((g16 & 1) << 2));
        f32x4 v = *(const f32x4*)(ep + row * 132 + col);
        ushort4 o;
        o.x = f2bf(v[0]); o.y = f2bf(v[1]); o.z = f2bf(v[2]); o.w = f2bf(v[3]);
        const int b_ = grow >> 8;
        const int tp = grow & 255;
        *(ushort4*)((unsigned short*)Cv +
                    ((size_t)((b_ * 3 + which) * HEADS + hbase + hh) * T_SEQ +
                     tp) * HD + g16 * 4) = o;
      } else {
        f32x4 v = *(const f32x4*)(ep + row * 132 + c4 * 4);
        const int gcol = n0 + c4 * 4;
        *(f32x4*)((float*)Cv + (size_t)grow * N + gcol) = v;
      }
    }
  }
}

// ---------------------------------------------------------------------------
// Banded causal attention via bf16 MFMA, fp32 softmax. qkv in attn panes
// [B][3][H][256][64], Q/K pre-swizzled: linear 1-KB DMA staging; V reads in
// one contiguous 8-KB pane window. Output y packed for GEMM2. (unchanged)
// ---------------------------------------------------------------------------
#define PSTR 68
__global__ __launch_bounds__(256) void attn_mfma(
    const unsigned short* __restrict__ qkv, unsigned short* __restrict__ y) {
  __shared__ unsigned short Qs[64 * 64];   // [qrow][d]  bf16, swizzled
  __shared__ unsigned short Ks[64 * 64];   // [key][d]   bf16, swizzled
  __shared__ unsigned short Vt[64 * 64];   // [d][key]   bf16, swizzled
  __shared__ float Pw[4][16 * PSTR];       // per-wave P; reused as y-stage

  const unsigned id  = blockIdx.x;
  const unsigned bid = (id & 7u) * (gridDim.x >> 3) + (id >> 3);
  const int qt  = bid & 3;
  const int h   = (bid >> 2) % HEADS;
  const int b   = bid / (4 * HEADS);
  const int t   = threadIdx.x;
  const int lane = t & 63;
  const int w    = t >> 6;
  const int quad = lane >> 4;
  const int m16  = lane & 15;
  const int sw   = m16 & 7;

  const unsigned short* Qpane =
      qkv + ((size_t)((b * 3 + 0) * HEADS + h) * T_SEQ) * HD;
  const unsigned short* Kpane =
      qkv + ((size_t)((b * 3 + 1) * HEADS + h) * T_SEQ) * HD;
  const unsigned short* Vpane =
      qkv + ((size_t)((b * 3 + 2) * HEADS + h) * T_SEQ) * HD;
  const int qg0 = qt * 64;

  // ---- stage Q (64x64 bf16): linear 1-KB DMA, swizzle pre-baked ----
#pragma unroll
  for (int i = 0; i < 2; ++i) {
    const int inst = w * 2 + i;
    __builtin_amdgcn_global_load_lds(
        (const gbl_void*)(Qpane + (size_t)qg0 * HD + inst * 512 + lane * 8),
        (lds_void*)(Qs + inst * 512), 16, 0, 0);
  }

  float m_r[4], l_r[4];
  f32x4 yacc[4];
#pragma unroll
  for (int r = 0; r < 4; ++r) { m_r[r] = -1e30f; l_r[r] = 0.f; }
#pragma unroll
  for (int dt = 0; dt < 4; ++dt) yacc[dt] = (f32x4){0.f, 0.f, 0.f, 0.f};

  const int nchunks  = (qt == 0) ? 1 : 2;
  const int kb_first = (qt == 0) ? 0 : (qg0 - 64);
  const int qrow_base = qg0 + w * 16 + quad * 4;

  for (int ch = 0; ch < nchunks; ++ch) {
    const int kb = kb_first + ch * 64;

    __syncthreads();  // drain staging; protect Ks/Vt from prior cross-wave reads

    // ---- stage K: linear 1-KB DMA, swizzle pre-baked ----
#pragma unroll
    for (int i = 0; i < 2; ++i) {
      const int inst = w * 2 + i;
      __builtin_amdgcn_global_load_lds(
          (const gbl_void*)(Kpane + (size_t)kb * HD + inst * 512 + lane * 8),
          (lds_void*)(Ks + inst * 512), 16, 0, 0);
    }
    // ---- stage V transposed, swizzled: Vt[d][pos] = keychunk pos^(d&7) ----
    {
      const int vkey = t & 63;
      const int kc = vkey >> 3, ke = vkey & 7;
      const int vd0  = (t >> 6) * 16;
      const unsigned short* gv = Vpane + (size_t)(kb + vkey) * HD + vd0;
#pragma unroll
      for (int u = 0; u < 4; ++u) {
        ushort4 vv = *(const ushort4*)(gv + u * 4);
#pragma unroll
        for (int jj = 0; jj < 4; ++jj) {
          const int d = vd0 + u * 4 + jj;
          const unsigned short val =
              (jj == 0) ? vv.x : (jj == 1) ? vv.y : (jj == 2) ? vv.z : vv.w;
          Vt[d * 64 + ((kc ^ (d & 7)) << 3) + ke] = val;
        }
      }
    }
    __syncthreads();

    // ---- QK^T: S[16q x 64key] ----
    f32x4 sacc[4];
#pragma unroll
    for (int nt = 0; nt < 4; ++nt) sacc[nt] = (f32x4){0.f, 0.f, 0.f, 0.f};
#pragma unroll
    for (int ks = 0; ks < 64; ks += 32) {
      const int cp = (((ks >> 3) + quad) ^ sw) << 3;
      bf16x8 aq = *(const bf16x8*)(Qs + (size_t)(w * 16 + m16) * 64 + cp);
#pragma unroll
      for (int nt = 0; nt < 4; ++nt) {
        bf16x8 kf = *(const bf16x8*)(Ks + (size_t)(nt * 16 + m16) * 64 + cp);
        sacc[nt] = __builtin_amdgcn_mfma_f32_16x16x32_bf16(aq, kf, sacc[nt], 0, 0, 0);
      }
    }

    // ---- scale + band mask (C-layout: row=quad*4+r, col=m16) ----
    float mc[4] = {-1e30f, -1e30f, -1e30f, -1e30f};
#pragma unroll
    for (int nt = 0; nt < 4; ++nt) {
      const int kg = kb + nt * 16 + m16;
#pragma unroll
      for (int r = 0; r < 4; ++r) {
        const int qg = qrow_base + r;
        const bool valid = (kg <= qg) && (qg - kg <= WIN);
        const float sv = valid ? (sacc[nt][r] * 0.125f) : -1e30f;
        sacc[nt][r] = sv;
        mc[r] = fmaxf(mc[r], sv);
      }
    }
#pragma unroll
    for (int r = 0; r < 4; ++r) {
#pragma unroll
      for (int x = 1; x <= 8; x <<= 1) mc[r] = fmaxf(mc[r], __shfl_xor(mc[r], x));
    }

    // ---- online softmax update ----
#pragma unroll
    for (int r = 0; r < 4; ++r) {
      const float mn    = fmaxf(m_r[r], mc[r]);
      const float alpha = __expf(m_r[r] - mn);
      m_r[r] = mn;
      l_r[r] *= alpha;
#pragma unroll
      for (int dt = 0; dt < 4; ++dt) yacc[dt][r] *= alpha;
      float ls = 0.f;
#pragma unroll
      for (int nt = 0; nt < 4; ++nt) {
        const float p = __expf(sacc[nt][r] - mn);
        sacc[nt][r] = p;
        ls += p;
      }
#pragma unroll
      for (int x = 1; x <= 8; x <<= 1) ls += __shfl_xor(ls, x);
      l_r[r] += ls;
    }

    // ---- write P (fp32) to per-wave LDS (wave-private) ----
#pragma unroll
    for (int nt = 0; nt < 4; ++nt)
#pragma unroll
      for (int r = 0; r < 4; ++r)
        Pw[w][(quad * 4 + r) * PSTR + nt * 16 + m16] = sacc[nt][r];

    // ---- PV: A = P-frag (fp32->bf16), B = Vt-frag ----
#pragma unroll
    for (int ks = 0; ks < 64; ks += 32) {
      f32x4 pa = *(const f32x4*)(&Pw[w][m16 * PSTR + ks + quad * 8]);
      f32x4 pb = *(const f32x4*)(&Pw[w][m16 * PSTR + ks + quad * 8 + 4]);
      bf16x8 ap;
#pragma unroll
      for (int j = 0; j < 4; ++j) {
        ap[j]     = (__bf16)pa[j];
        ap[4 + j] = (__bf16)pb[j];
      }
      const int cp = (((ks >> 3) + quad) ^ sw) << 3;
#pragma unroll
      for (int dt = 0; dt < 4; ++dt) {
        bf16x8 vf = *(const bf16x8*)(Vt + (size_t)(dt * 16 + m16) * 64 + cp);
        yacc[dt] = __builtin_amdgcn_mfma_f32_16x16x32_bf16(ap, vf, yacc[dt], 0, 0, 0);
      }
    }
  }

  // ---- epilogue: stage y/l into Pw (wave-local region), packed stores ----
  float* epy = &Pw[0][0];  // viewed as [64 rows][68]; rows w*16.. are Pw[w]
  float inv[4];
#pragma unroll
  for (int r = 0; r < 4; ++r) inv[r] = 1.f / l_r[r];
#pragma unroll
  for (int dt = 0; dt < 4; ++dt)
#pragma unroll
    for (int r = 0; r < 4; ++r)
      epy[(w * 16 + quad * 4 + r) * PSTR + dt * 16 + m16] = yacc[dt][r] * inv[r];
  __syncthreads();
  // 64 rows x 16 ushort4-chunks = 1024 chunks, 4 per thread.
  // Store into PACKED pre-swizzled y layout [M/128][12][128][32].
#pragma unroll
  for (int cc = 0; cc < 4; ++cc) {
    const int chunk = cc * 256 + t;
    const int row = chunk >> 4;
    const int c4  = chunk & 15;
    f32x4 v = *(const f32x4*)(epy + row * PSTR + c4 * 4);
    ushort4 o;
    o.x = f2bf(v[0]); o.y = f2bf(v[1]); o.z = f2bf(v[2]); o.w = f2bf(v[3]);
    const int m = b * T_SEQ + qg0 + row;   // global row
    const int c = h * HD + c4 * 4;         // global col
    const int kc = c >> 5;
    const int u  = (c >> 3) & 3;
    const int p  = u ^ ((m & 7) >> 1);
    *(ushort4*)(y + ((size_t)(m >> 7) * 12 + kc) * 4096 + (m & 127) * 32 +
                p * 8 + (c & 7)) = o;
  }
}

// ---------------------------------------------------------------------------
extern "C" void kernel_launch(void* const* d_in, const int* in_sizes, int n_in,
                              void* d_out, int out_size, void* d_ws, size_t ws_size,
                              hipStream_t stream) {
  const float* x      = (const float*)d_in[0];
  const float* W_attn = (const float*)d_in[1];
  const float* b_attn = (const float*)d_in[2];
  const float* W_proj = (const float*)d_in[3];
  const float* b_proj = (const float*)d_in[4];
  float* out = (float*)d_out;

  const int M = B_SZ * T_SEQ;  // 32768

  unsigned short* qkv_b = (unsigned short*)d_ws;            // M*1152 bf16 (attn panes)
  unsigned short* y_b   = qkv_b + (size_t)M * (3 * C_DIM);  // M*384 (packed)
  unsigned short* x_b   = y_b   + (size_t)M * C_DIM;        // M*384 (packed)
  unsigned short* Wa_t  = x_b   + (size_t)M * C_DIM;        // 1152*384 (packed)
  unsigned short* Wp_t  = Wa_t  + (size_t)(3 * C_DIM) * C_DIM;  // 384*384 (packed)

  // 0) converts + packing
  {
    convert_pack_f32_bf16<<<dim3(M * 48 / 256), 256, 0, stream>>>(x, x_b);
    transpose_convert_pack<<<dim3((3 * C_DIM) / 32, C_DIM / 32), dim3(32, 8), 0,
                             stream>>>(W_attn, Wa_t, C_DIM, 3 * C_DIM);
    transpose_convert_pack<<<dim3(C_DIM / 32, C_DIM / 32), dim3(32, 8), 0,
                             stream>>>(W_proj, Wp_t, C_DIM, C_DIM);
  }

  // 1) qkv(bf16, attn panes) = x @ W_attn + b_attn  [32768x1152], 128x9 blocks
  gemm_mfma_bf16<true, C_DIM><<<dim3(9 * (M / 256)), 512, 0, stream>>>(
      x_b, Wa_t, b_attn, qkv_b, M, 3 * C_DIM, 9);

  // 2) banded causal attention -> y(bf16, packed) [32768 x 384]
  attn_mfma<<<dim3(B_SZ * HEADS * (T_SEQ / 64)), 256, 0, stream>>>(qkv_b, y_b);

  // 3) out(fp32) = y @ W_proj + b_proj  [32768 x 384], 128x3 blocks
  gemm_mfma_bf16<false, C_DIM><<<dim3(3 * (M / 256)), 512, 0, stream>>>(
      y_b, Wp_t, b_proj, out, M, C_DIM, 3);
}